// Round 1
// baseline (1750.163 us; speedup 1.0000x reference)
//
#include <hip/hip_runtime.h>

// Problem constants
#define NC   5
#define NU   6144
#define NV   6144
#define ND   64
#define NB   4096
#define CAP  128   // max nnz per row/col per class (mean 61.4, +8.5 sigma)

// ---------------------------------------------------------------------------
// Pass 1: dense adj [C,U,V] fp32 (values exactly 0.0/1.0) -> CSR + CSC lists.
// Each thread handles 4 float4 chunks (coalesced across lanes per load).
// ---------------------------------------------------------------------------
__global__ __launch_bounds__(256) void k_sparsify(
    const float4* __restrict__ adj4,
    int* __restrict__ csr_cnt, unsigned short* __restrict__ csr_idx,
    int* __restrict__ csc_cnt, unsigned short* __restrict__ csc_idx) {
  const unsigned int nthreads = 46080u * 256u;          // 11,796,480
  const unsigned int tid = blockIdx.x * 256u + threadIdx.x;
  #pragma unroll
  for (int k = 0; k < 4; ++k) {
    const unsigned int f4 = tid + (unsigned int)k * nthreads;  // < 47,185,920
    const float4 a = adj4[f4];
    if (a.x + a.y + a.z + a.w != 0.0f) {               // values are 0/1: exact
      const unsigned int e  = f4 * 4u;                 // flat element idx < 2^31
      const unsigned int cu = e / (unsigned int)NV;    // c*U + u
      const unsigned int v0 = e - cu * (unsigned int)NV;
      const unsigned int c  = cu / (unsigned int)NU;
      const float vals[4] = {a.x, a.y, a.z, a.w};
      #pragma unroll
      for (int i = 0; i < 4; ++i) {
        if (vals[i] != 0.0f) {
          const unsigned int v = v0 + (unsigned int)i;
          const int pr = atomicAdd(&csr_cnt[cu], 1);
          if (pr < CAP) csr_idx[(size_t)cu * CAP + pr] = (unsigned short)v;
          const unsigned int cv = c * (unsigned int)NV + v;
          const int pc = atomicAdd(&csc_cnt[cv], 1);
          if (pc < CAP) csc_idx[(size_t)cv * CAP + pc] =
              (unsigned short)(cu - c * (unsigned int)NU);
        }
      }
    }
  }
}

// ---------------------------------------------------------------------------
// Dense transform: out[c,r,e] = sum_d emb[r,d] * W[c,d,e]
// Block = 256 (4 waves); each lane holds W[c,:,e] in 64 VGPRs; emb row reads
// are wave-uniform -> scalar loads. Grid: (N/64, C).
// ---------------------------------------------------------------------------
__global__ __launch_bounds__(256) void k_emb_transform(
    const float* __restrict__ emb,   // N x 64
    const float* __restrict__ W,     // C x 64 x 64
    float* __restrict__ out,         // C x N x 64
    int N) {
  const int c    = blockIdx.y;
  const int lane = threadIdx.x & 63;
  const int wave = threadIdx.x >> 6;
  const float* Wc = W + c * 64 * 64;
  float w[64];
  #pragma unroll
  for (int d = 0; d < 64; ++d) w[d] = Wc[d * 64 + lane];   // coalesced
  const int row0 = blockIdx.x * 64 + wave;
  for (int i = 0; i < 16; ++i) {
    const int r = row0 + i * 4;
    const float* er = emb + (size_t)r * 64;                // wave-uniform
    float acc = 0.0f;
    #pragma unroll
    for (int d = 0; d < 64; ++d) acc = fmaf(er[d], w[d], acc);
    out[((size_t)c * N + r) * 64 + lane] = acc;
  }
}

// ---------------------------------------------------------------------------
// SpMM gather: out[r,e] = act( sum_c sum_{j in list(c,r)} msg[c, j, e]
//                              + sum_c bias[c,e] )
// One wave per output row; lane = e. Gathers are 256B coalesced rows from the
// L2-resident msg buffer. Index list read as packed u32 (wave-uniform).
// ---------------------------------------------------------------------------
__global__ __launch_bounds__(256) void k_spmm(
    const int* __restrict__ cnt,             // C x M
    const unsigned short* __restrict__ idx,  // C x M x CAP
    const float* __restrict__ msg,           // C x N x 64
    const float* __restrict__ bias,          // C x 64
    float* __restrict__ out,                 // M x 64
    int M, int N, int do_relu) {
  const int lane = threadIdx.x & 63;
  const int wave = threadIdx.x >> 6;
  const int r = blockIdx.x * 4 + wave;
  float acc = 0.0f;
  #pragma unroll
  for (int c = 0; c < NC; ++c) acc += bias[c * 64 + lane];
  for (int c = 0; c < NC; ++c) {
    int n = cnt[c * M + r];
    n = n > CAP ? CAP : n;
    const unsigned int* l32 =
        (const unsigned int*)(idx + (size_t)(c * M + r) * CAP);
    const float* msgc = msg + (size_t)c * N * 64 + lane;
    int i = 0;
    for (; i + 2 <= n; i += 2) {
      const unsigned int pr = l32[i >> 1];
      acc += msgc[(pr & 0xffffu) * 64];
      acc += msgc[(pr >> 16) * 64];
    }
    if (i < n) {
      const unsigned int pr = l32[i >> 1];
      acc += msgc[(pr & 0xffffu) * 64];
    }
  }
  if (do_relu) acc = fmaxf(acc, 0.0f);
  out[(size_t)r * 64 + lane] = acc;
}

// ---------------------------------------------------------------------------
// Decoder: logits[b,c] = sum_{d,e} z_u[u[b],d] * Q[c,d,e] * z_v[v[b],e]
// One wave per pair b; lane = e; wave shuffle-reduce over e.
// ---------------------------------------------------------------------------
__global__ __launch_bounds__(256) void k_decoder(
    const int* __restrict__ uu, const int* __restrict__ vv,
    const float* __restrict__ z_u, const float* __restrict__ z_v,
    const float* __restrict__ Q,   // C x 64 x 64
    float* __restrict__ out) {     // B x C
  const int lane = threadIdx.x & 63;
  const int wave = threadIdx.x >> 6;
  const int b = blockIdx.x * 4 + wave;
  const int ub = uu[b];
  const int vb = vv[b];
  const float zve = z_v[(size_t)vb * 64 + lane];
  const float* zu = z_u + (size_t)ub * 64;            // wave-uniform reads
  #pragma unroll
  for (int c = 0; c < NC; ++c) {
    const float* Qc = Q + c * 64 * 64;
    float t = 0.0f;
    #pragma unroll
    for (int d = 0; d < 64; ++d) t = fmaf(zu[d], Qc[d * 64 + lane], t);
    float p = t * zve;
    #pragma unroll
    for (int off = 32; off > 0; off >>= 1) p += __shfl_xor(p, off, 64);
    if (lane == 0) out[(size_t)b * NC + c] = p;
  }
}

extern "C" void kernel_launch(void* const* d_in, const int* in_sizes, int n_in,
                              void* d_out, int out_size, void* d_ws, size_t ws_size,
                              hipStream_t stream) {
  const int*   u     = (const int*)d_in[0];
  const int*   v     = (const int*)d_in[1];
  const float* u_emb = (const float*)d_in[2];
  const float* v_emb = (const float*)d_in[3];
  const float* W1u   = (const float*)d_in[4];
  const float* b1u   = (const float*)d_in[5];
  const float* W1v   = (const float*)d_in[6];
  const float* b1v   = (const float*)d_in[7];
  const float* W2u   = (const float*)d_in[8];
  const float* b2u   = (const float*)d_in[9];
  const float* W2v   = (const float*)d_in[10];
  const float* b2v   = (const float*)d_in[11];
  const float* Q     = (const float*)d_in[12];
  const float* adj   = (const float*)d_in[13];
  float* out = (float*)d_out;

  // ---- workspace carve-up (~38 MB) ----
  char* ws = (char*)d_ws;
  size_t off = 0;
  auto alloc = [&](size_t bytes) -> void* {
    void* p = ws + off;
    off += (bytes + 255) & ~(size_t)255;
    return p;
  };
  int* cnts = (int*)alloc((size_t)2 * NC * NU * sizeof(int));  // csr | csc
  int* csr_cnt = cnts;
  int* csc_cnt = cnts + NC * NU;
  unsigned short* csr_idx = (unsigned short*)alloc((size_t)NC * NU * CAP * 2);
  unsigned short* csc_idx = (unsigned short*)alloc((size_t)NC * NV * CAP * 2);
  float* msgA = (float*)alloc((size_t)NC * NV * ND * 4);  // msg1v, then msg2u
  float* msgB = (float*)alloc((size_t)NC * NU * ND * 4);  // msg1u, then msg2v
  float* h_u  = (float*)alloc((size_t)NU * ND * 4);
  float* h_v  = (float*)alloc((size_t)NV * ND * 4);
  float* z_u  = (float*)alloc((size_t)NU * ND * 4);
  float* z_v  = (float*)alloc((size_t)NV * ND * 4);

  // zero the nnz counters (ws is poisoned 0xAA each call)
  hipMemsetAsync(cnts, 0, (size_t)2 * NC * NU * sizeof(int), stream);

  // Pass 1: single read of dense adj -> CSR + CSC
  k_sparsify<<<46080, 256, 0, stream>>>((const float4*)adj,
                                        csr_cnt, csr_idx, csc_cnt, csc_idx);

  const dim3 gT(NU / 64, NC);
  // layer 1 messages
  k_emb_transform<<<gT, 256, 0, stream>>>(v_emb, W1v, msgA, NV);
  k_emb_transform<<<gT, 256, 0, stream>>>(u_emb, W1u, msgB, NU);
  // layer 1 aggregation (+bias, relu)
  k_spmm<<<NU / 4, 256, 0, stream>>>(csr_cnt, csr_idx, msgA, b1v, h_u, NU, NV, 1);
  k_spmm<<<NV / 4, 256, 0, stream>>>(csc_cnt, csc_idx, msgB, b1u, h_v, NV, NU, 1);
  // layer 2 messages (reuse msg buffers)
  k_emb_transform<<<gT, 256, 0, stream>>>(h_v, W2u, msgA, NV);
  k_emb_transform<<<gT, 256, 0, stream>>>(h_u, W2v, msgB, NU);
  // layer 2 aggregation (+bias, no relu)
  k_spmm<<<NU / 4, 256, 0, stream>>>(csr_cnt, csr_idx, msgA, b2u, z_u, NU, NV, 0);
  k_spmm<<<NV / 4, 256, 0, stream>>>(csc_cnt, csc_idx, msgB, b2v, z_v, NV, NU, 0);
  // bilinear decoder
  k_decoder<<<NB / 4, 256, 0, stream>>>(u, v, z_u, z_v, Q, out);
}

// Round 2
// 1387.807 us; speedup vs baseline: 1.2611x; 1.2611x over previous
//
#include <hip/hip_runtime.h>

// Problem constants
#define NC   5
#define NU   6144
#define NV   6144
#define ND   64
#define NB   4096
#define CAP  128   // max nnz per row/col per class (mean 61.4, +8.5 sigma)
#define NW   192   // bitmask words per row (6144/32)

// spread bits of a byte to every 4th bit of a u32
__device__ __forceinline__ unsigned int spread4(unsigned int x) {
  x &= 0xFFu;
  x = (x | (x << 12)) & 0x000F000Fu;
  x = (x | (x << 6))  & 0x03030303u;
  x = (x | (x << 3))  & 0x11111111u;
  return x;
}

// ---------------------------------------------------------------------------
// Pass 1: dense adj [C,U,V] fp32 (exactly 0/1) -> row-major + col-major
// bitmasks. Tile = 64 u x 256 v. Each wave handles 16 rows; per row one
// fully-coalesced 1KB float4 load (lane = 16B chunk), 4 ballots -> 8 words.
// LDS bit-transpose produces the column words. No atomics, no divergence.
// ---------------------------------------------------------------------------
__global__ __launch_bounds__(256) void k_bitmask(
    const float* __restrict__ adj,
    unsigned int* __restrict__ rowmask,   // [C*U][192] words, bit = v
    unsigned int* __restrict__ colmask) { // [C*V][192] words, bit = u
  __shared__ unsigned int rowwords[64][8];
  const int b = blockIdx.x;              // 5 * 96 * 24 tiles
  const int c  = b / 2304;
  const int rem = b - c * 2304;
  const int tu = rem / 24;
  const int tv = rem - tu * 24;
  const int wave = threadIdx.x >> 6;
  const int lane = threadIdx.x & 63;

  // ---- row phase: 16 rows per wave, ballot-pack bits ----
  for (int rr = 0; rr < 16; ++rr) {
    const int r = wave * 16 + rr;        // 0..63 within tile
    const float4* src = (const float4*)(adj +
        ((size_t)(c * NU + tu * 64 + r) * NV + tv * 256));
    const float4 a = src[lane];
    const unsigned long long b0 = __ballot(a.x != 0.0f);
    const unsigned long long b1 = __ballot(a.y != 0.0f);
    const unsigned long long b2 = __ballot(a.z != 0.0f);
    const unsigned long long b3 = __ballot(a.w != 0.0f);
    if (lane < 8) {                      // word w = lane covers lanes w*8..w*8+7
      const unsigned int e0 = spread4((unsigned int)(b0 >> (lane * 8)));
      const unsigned int e1 = spread4((unsigned int)(b1 >> (lane * 8)));
      const unsigned int e2 = spread4((unsigned int)(b2 >> (lane * 8)));
      const unsigned int e3 = spread4((unsigned int)(b3 >> (lane * 8)));
      rowwords[r][lane] = e0 | (e1 << 1) | (e2 << 2) | (e3 << 3);
    }
  }
  __syncthreads();

  // ---- rowmask write: 64 rows x 8 words, 32B contiguous per row ----
  {
    const int r2 = threadIdx.x >> 2;     // row 0..63
    const int k  = threadIdx.x & 3;      // word pair 0..3
    uint2 w;
    w.x = rowwords[r2][k * 2 + 0];
    w.y = rowwords[r2][k * 2 + 1];
    *(uint2*)(rowmask + (size_t)(c * NU + tu * 64 + r2) * NW + tv * 8 + k * 2) = w;
  }

  // ---- colmask: bit-transpose, thread = column j (0..255) ----
  {
    const int j = threadIdx.x;
    const int w = j >> 5, bit = j & 31;
    unsigned int w0 = 0, w1 = 0;
    #pragma unroll
    for (int r = 0; r < 32; ++r) {
      w0 |= ((rowwords[r][w]      >> bit) & 1u) << r;
      w1 |= ((rowwords[r + 32][w] >> bit) & 1u) << r;
    }
    uint2 ww; ww.x = w0; ww.y = w1;
    *(uint2*)(colmask + (size_t)(c * NV + tv * 256 + j) * NW + tu * 2) = ww;
  }
}

// ---------------------------------------------------------------------------
// Pass 2: bitmask row -> index list + count, no atomics.
// One wave per row; lane owns words {lane, lane+64, lane+128}; wave prefix
// sums give each word's write offset; lanes expand their bits in parallel.
// ---------------------------------------------------------------------------
__global__ __launch_bounds__(256) void k_expand(
    const unsigned int* __restrict__ mask,  // [R][192]
    int* __restrict__ cnt,                  // [R]
    unsigned short* __restrict__ idx) {     // [R][CAP]
  const int wave = threadIdx.x >> 6;
  const int lane = threadIdx.x & 63;
  const int R = blockIdx.x * 4 + wave;
  const unsigned int* mrow = mask + (size_t)R * NW;
  const unsigned int w0 = mrow[lane];
  const unsigned int w1 = mrow[lane + 64];
  const unsigned int w2 = mrow[lane + 128];
  const int t0 = __popc(w0), t1 = __popc(w1), t2 = __popc(w2);
  int p0 = t0, p1 = t1, p2 = t2;         // inclusive prefix over lanes
  #pragma unroll
  for (int d = 1; d < 64; d <<= 1) {
    const int y0 = __shfl_up(p0, d, 64);
    const int y1 = __shfl_up(p1, d, 64);
    const int y2 = __shfl_up(p2, d, 64);
    if (lane >= d) { p0 += y0; p1 += y1; p2 += y2; }
  }
  const int T0 = __shfl(p0, 63, 64);
  const int T1 = __shfl(p1, 63, 64);
  const int T2 = __shfl(p2, 63, 64);
  if (lane == 0) cnt[R] = T0 + T1 + T2;
  unsigned short* orow = idx + (size_t)R * CAP;
  int e0 = p0 - t0;                      // exclusive offsets, word order
  int e1 = T0 + p1 - t1;
  int e2 = T0 + T1 + p2 - t2;
  unsigned int m;
  m = w0;
  while (m) { int bb = __ffs(m) - 1; if (e0 < CAP) orow[e0] = (unsigned short)(lane * 32 + bb); ++e0; m &= m - 1; }
  m = w1;
  while (m) { int bb = __ffs(m) - 1; if (e1 < CAP) orow[e1] = (unsigned short)((lane + 64) * 32 + bb); ++e1; m &= m - 1; }
  m = w2;
  while (m) { int bb = __ffs(m) - 1; if (e2 < CAP) orow[e2] = (unsigned short)((lane + 128) * 32 + bb); ++e2; m &= m - 1; }
}

// ---------------------------------------------------------------------------
// Dense transform: out[c,r,e] = sum_d emb[r,d] * W[c,d,e]
// ---------------------------------------------------------------------------
__global__ __launch_bounds__(256) void k_emb_transform(
    const float* __restrict__ emb,   // N x 64
    const float* __restrict__ W,     // C x 64 x 64
    float* __restrict__ out,         // C x N x 64
    int N) {
  const int c    = blockIdx.y;
  const int lane = threadIdx.x & 63;
  const int wave = threadIdx.x >> 6;
  const float* Wc = W + c * 64 * 64;
  float w[64];
  #pragma unroll
  for (int d = 0; d < 64; ++d) w[d] = Wc[d * 64 + lane];   // coalesced
  const int row0 = blockIdx.x * 64 + wave;
  for (int i = 0; i < 16; ++i) {
    const int r = row0 + i * 4;
    const float* er = emb + (size_t)r * 64;                // wave-uniform
    float acc = 0.0f;
    #pragma unroll
    for (int d = 0; d < 64; ++d) acc = fmaf(er[d], w[d], acc);
    out[((size_t)c * N + r) * 64 + lane] = acc;
  }
}

// ---------------------------------------------------------------------------
// SpMM gather: out[r,:] = act( sum_c sum_{j in list(c,r)} msg[c,j,:] + bias )
// One block per row. Classes split across the 4 waves (c = wave, wave+4).
// Within a wave: 4 gather-groups of 16 lanes; each group reads one msg row
// as float4 (16 lanes x 16B = 256B) -> 4 rows gathered per load instruction.
// ---------------------------------------------------------------------------
__global__ __launch_bounds__(256) void k_spmm(
    const int* __restrict__ cnt,             // C x M
    const unsigned short* __restrict__ idx,  // C x M x CAP
    const float* __restrict__ msg,           // C x N x 64
    const float* __restrict__ bias,          // C x 64
    float* __restrict__ out,                 // M x 64
    int M, int N, int do_relu) {
  __shared__ float4 red4[4][16];
  const int r    = blockIdx.x;
  const int wave = threadIdx.x >> 6;
  const int lane = threadIdx.x & 63;
  const int g    = lane >> 4;       // gather group 0..3
  const int e16  = lane & 15;       // 16B chunk of the 256B row
  float4 acc = make_float4(0.f, 0.f, 0.f, 0.f);
  for (int c = wave; c < NC; c += 4) {
    int n = cnt[c * M + r];
    n = n > CAP ? CAP : n;
    const unsigned short* l = idx + (size_t)(c * M + r) * CAP;
    const float4* msgc = (const float4*)msg + (size_t)c * N * 16;
    for (int i = 0; i < n; i += 4) {
      const int ig = i + g;
      if (ig < n) {
        const float4 x = msgc[(int)l[ig] * 16 + e16];
        acc.x += x.x; acc.y += x.y; acc.z += x.z; acc.w += x.w;
      }
    }
  }
  // reduce the 4 gather groups within the wave (xor 16, 32)
  #pragma unroll
  for (int off = 16; off < 64; off <<= 1) {
    acc.x += __shfl_xor(acc.x, off, 64);
    acc.y += __shfl_xor(acc.y, off, 64);
    acc.z += __shfl_xor(acc.z, off, 64);
    acc.w += __shfl_xor(acc.w, off, 64);
  }
  if (lane < 16) red4[wave][e16] = acc;
  __syncthreads();
  if (threadIdx.x < 16) {
    const int e = threadIdx.x;
    float4 s = red4[0][e];
    #pragma unroll
    for (int w = 1; w < 4; ++w) {
      s.x += red4[w][e].x; s.y += red4[w][e].y;
      s.z += red4[w][e].z; s.w += red4[w][e].w;
    }
    #pragma unroll
    for (int c = 0; c < NC; ++c) {
      const float4 bb = ((const float4*)bias)[c * 16 + e];
      s.x += bb.x; s.y += bb.y; s.z += bb.z; s.w += bb.w;
    }
    if (do_relu) {
      s.x = fmaxf(s.x, 0.f); s.y = fmaxf(s.y, 0.f);
      s.z = fmaxf(s.z, 0.f); s.w = fmaxf(s.w, 0.f);
    }
    ((float4*)out)[(size_t)r * 16 + e] = s;
  }
}

// ---------------------------------------------------------------------------
// Decoder: logits[b,c] = sum_{d,e} z_u[u[b],d] * Q[c,d,e] * z_v[v[b],e]
// ---------------------------------------------------------------------------
__global__ __launch_bounds__(256) void k_decoder(
    const int* __restrict__ uu, const int* __restrict__ vv,
    const float* __restrict__ z_u, const float* __restrict__ z_v,
    const float* __restrict__ Q,   // C x 64 x 64
    float* __restrict__ out) {     // B x C
  const int lane = threadIdx.x & 63;
  const int wave = threadIdx.x >> 6;
  const int b = blockIdx.x * 4 + wave;
  const int ub = uu[b];
  const int vb = vv[b];
  const float zve = z_v[(size_t)vb * 64 + lane];
  const float* zu = z_u + (size_t)ub * 64;            // wave-uniform reads
  #pragma unroll
  for (int c = 0; c < NC; ++c) {
    const float* Qc = Q + c * 64 * 64;
    float t = 0.0f;
    #pragma unroll
    for (int d = 0; d < 64; ++d) t = fmaf(zu[d], Qc[d * 64 + lane], t);
    float p = t * zve;
    #pragma unroll
    for (int off = 32; off > 0; off >>= 1) p += __shfl_xor(p, off, 64);
    if (lane == 0) out[(size_t)b * NC + c] = p;
  }
}

extern "C" void kernel_launch(void* const* d_in, const int* in_sizes, int n_in,
                              void* d_out, int out_size, void* d_ws, size_t ws_size,
                              hipStream_t stream) {
  const int*   u     = (const int*)d_in[0];
  const int*   v     = (const int*)d_in[1];
  const float* u_emb = (const float*)d_in[2];
  const float* v_emb = (const float*)d_in[3];
  const float* W1u   = (const float*)d_in[4];
  const float* b1u   = (const float*)d_in[5];
  const float* W1v   = (const float*)d_in[6];
  const float* b1v   = (const float*)d_in[7];
  const float* W2u   = (const float*)d_in[8];
  const float* b2u   = (const float*)d_in[9];
  const float* W2v   = (const float*)d_in[10];
  const float* b2v   = (const float*)d_in[11];
  const float* Q     = (const float*)d_in[12];
  const float* adj   = (const float*)d_in[13];
  float* out = (float*)d_out;

  // ---- workspace carve-up (~63.2 MB) ----
  char* ws = (char*)d_ws;
  int* csr_cnt = (int*)ws;                                   // 5*6144 ints
  int* csc_cnt = csr_cnt + NC * NU;                          //  (245,760 B)
  unsigned short* csr_idx = (unsigned short*)(ws + 245760);  // 7,864,320 B
  unsigned short* csc_idx = (unsigned short*)(ws + 245760 + 7864320);
  char* maskbase = ws + 245760 + 2 * 7864320;
  unsigned int* rowmask = (unsigned int*)maskbase;           // 23,592,960 B
  unsigned int* colmask = (unsigned int*)(maskbase + 23592960);
  // msg/h/z buffers alias the rowmask region (dead after k_expand):
  float* msgA = (float*)maskbase;                            // 7,864,320 B
  float* msgB = (float*)(maskbase + 7864320);                // 7,864,320 B
  float* h_u  = (float*)(maskbase + 15728640);               // 1,572,864 B
  float* h_v  = (float*)(maskbase + 17301504);
  float* z_u  = (float*)(maskbase + 18874368);
  float* z_v  = (float*)(maskbase + 20447232);               // ends 22,020,096

  // Pass 1: single coalesced read of dense adj -> row/col bitmasks
  k_bitmask<<<5 * 96 * 24, 256, 0, stream>>>(adj, rowmask, colmask);
  // Pass 2: bitmasks -> CSR / CSC (atomic-free)
  k_expand<<<NC * NU / 4, 256, 0, stream>>>(rowmask, csr_cnt, csr_idx);
  k_expand<<<NC * NV / 4, 256, 0, stream>>>(colmask, csc_cnt, csc_idx);

  const dim3 gT(NU / 64, NC);
  // layer 1 messages (msgA overwrites rowmask -- dead by now)
  k_emb_transform<<<gT, 256, 0, stream>>>(v_emb, W1v, msgA, NV);
  k_emb_transform<<<gT, 256, 0, stream>>>(u_emb, W1u, msgB, NU);
  // layer 1 aggregation (+bias, relu)
  k_spmm<<<NU, 256, 0, stream>>>(csr_cnt, csr_idx, msgA, b1v, h_u, NU, NV, 1);
  k_spmm<<<NV, 256, 0, stream>>>(csc_cnt, csc_idx, msgB, b1u, h_v, NV, NU, 1);
  // layer 2 messages
  k_emb_transform<<<gT, 256, 0, stream>>>(h_v, W2u, msgA, NV);
  k_emb_transform<<<gT, 256, 0, stream>>>(h_u, W2v, msgB, NU);
  // layer 2 aggregation (+bias, no relu)
  k_spmm<<<NU, 256, 0, stream>>>(csr_cnt, csr_idx, msgA, b2u, z_u, NU, NV, 0);
  k_spmm<<<NV, 256, 0, stream>>>(csc_cnt, csc_idx, msgB, b2v, z_v, NV, NU, 0);
  // bilinear decoder
  k_decoder<<<NB / 4, 256, 0, stream>>>(u, v, z_u, z_v, Q, out);
}

// Round 3
// 1262.806 us; speedup vs baseline: 1.3859x; 1.0990x over previous
//
#include <hip/hip_runtime.h>

// Problem constants
#define NC   5
#define NU   6144
#define NV   6144
#define ND   64
#define NB   4096
#define CAP  128   // max nnz per row/col per class (mean 61.4, +8.5 sigma)
#define NW   192   // bitmask words per row (6144/32)

// spread bits of a byte to every 4th bit of a u32
__device__ __forceinline__ unsigned int spread4(unsigned int x) {
  x &= 0xFFu;
  x = (x | (x << 12)) & 0x000F000Fu;
  x = (x | (x << 6))  & 0x03030303u;
  x = (x | (x << 3))  & 0x11111111u;
  return x;
}

// ---------------------------------------------------------------------------
// Pass 1: dense adj [C,U,V] fp32 (exactly 0/1) -> row-major + col-major
// bitmasks. Tile = 64 u x 256 v. Each wave: preload 16 rows (16 float4 loads
// in flight), then ballot-pack. LDS bit-transpose for column words.
// ---------------------------------------------------------------------------
__global__ __launch_bounds__(256) void k_bitmask(
    const float* __restrict__ adj,
    unsigned int* __restrict__ rowmask,   // [C*U][192] words, bit = v
    unsigned int* __restrict__ colmask) { // [C*V][192] words, bit = u
  __shared__ unsigned int rowwords[64][8];
  const int b = blockIdx.x;              // 5 * 96 * 24 tiles
  const int c  = b / 2304;
  const int rem = b - c * 2304;
  const int tu = rem / 24;
  const int tv = rem - tu * 24;
  const int wave = threadIdx.x >> 6;
  const int lane = threadIdx.x & 63;

  // ---- row phase: preload 16 rows, then pack ----
  float4 av[16];
  {
    const float* base = adj +
        ((size_t)(c * NU + tu * 64 + wave * 16) * NV + tv * 256);
    #pragma unroll
    for (int rr = 0; rr < 16; ++rr)
      av[rr] = ((const float4*)(base + (size_t)rr * NV))[lane];
  }
  #pragma unroll
  for (int rr = 0; rr < 16; ++rr) {
    const unsigned long long b0 = __ballot(av[rr].x != 0.0f);
    const unsigned long long b1 = __ballot(av[rr].y != 0.0f);
    const unsigned long long b2 = __ballot(av[rr].z != 0.0f);
    const unsigned long long b3 = __ballot(av[rr].w != 0.0f);
    if (lane < 8) {                      // word w = lane covers lanes w*8..w*8+7
      const unsigned int e0 = spread4((unsigned int)(b0 >> (lane * 8)));
      const unsigned int e1 = spread4((unsigned int)(b1 >> (lane * 8)));
      const unsigned int e2 = spread4((unsigned int)(b2 >> (lane * 8)));
      const unsigned int e3 = spread4((unsigned int)(b3 >> (lane * 8)));
      rowwords[wave * 16 + rr][lane] = e0 | (e1 << 1) | (e2 << 2) | (e3 << 3);
    }
  }
  __syncthreads();

  // ---- rowmask write: 64 rows x 8 words, 32B contiguous per row ----
  {
    const int r2 = threadIdx.x >> 2;     // row 0..63
    const int k  = threadIdx.x & 3;      // word pair 0..3
    uint2 w;
    w.x = rowwords[r2][k * 2 + 0];
    w.y = rowwords[r2][k * 2 + 1];
    *(uint2*)(rowmask + (size_t)(c * NU + tu * 64 + r2) * NW + tv * 8 + k * 2) = w;
  }

  // ---- colmask: bit-transpose, thread = column j (0..255) ----
  {
    const int j = threadIdx.x;
    const int w = j >> 5, bit = j & 31;
    unsigned int w0 = 0, w1 = 0;
    #pragma unroll
    for (int r = 0; r < 32; ++r) {
      w0 |= ((rowwords[r][w]      >> bit) & 1u) << r;
      w1 |= ((rowwords[r + 32][w] >> bit) & 1u) << r;
    }
    uint2 ww; ww.x = w0; ww.y = w1;
    *(uint2*)(colmask + (size_t)(c * NV + tv * 256 + j) * NW + tu * 2) = ww;
  }
}

// ---------------------------------------------------------------------------
// Pass 2: bitmask row -> index list + count, no atomics.
// ---------------------------------------------------------------------------
__global__ __launch_bounds__(256) void k_expand(
    const unsigned int* __restrict__ mask,  // [R][192]
    int* __restrict__ cnt,                  // [R]
    unsigned short* __restrict__ idx) {     // [R][CAP]
  const int wave = threadIdx.x >> 6;
  const int lane = threadIdx.x & 63;
  const int R = blockIdx.x * 4 + wave;
  const unsigned int* mrow = mask + (size_t)R * NW;
  const unsigned int w0 = mrow[lane];
  const unsigned int w1 = mrow[lane + 64];
  const unsigned int w2 = mrow[lane + 128];
  const int t0 = __popc(w0), t1 = __popc(w1), t2 = __popc(w2);
  int p0 = t0, p1 = t1, p2 = t2;         // inclusive prefix over lanes
  #pragma unroll
  for (int d = 1; d < 64; d <<= 1) {
    const int y0 = __shfl_up(p0, d, 64);
    const int y1 = __shfl_up(p1, d, 64);
    const int y2 = __shfl_up(p2, d, 64);
    if (lane >= d) { p0 += y0; p1 += y1; p2 += y2; }
  }
  const int T0 = __shfl(p0, 63, 64);
  const int T1 = __shfl(p1, 63, 64);
  const int T2 = __shfl(p2, 63, 64);
  if (lane == 0) cnt[R] = T0 + T1 + T2;
  unsigned short* orow = idx + (size_t)R * CAP;
  int e0 = p0 - t0;                      // exclusive offsets, word order
  int e1 = T0 + p1 - t1;
  int e2 = T0 + T1 + p2 - t2;
  unsigned int m;
  m = w0;
  while (m) { int bb = __ffs(m) - 1; if (e0 < CAP) orow[e0] = (unsigned short)(lane * 32 + bb); ++e0; m &= m - 1; }
  m = w1;
  while (m) { int bb = __ffs(m) - 1; if (e1 < CAP) orow[e1] = (unsigned short)((lane + 64) * 32 + bb); ++e1; m &= m - 1; }
  m = w2;
  while (m) { int bb = __ffs(m) - 1; if (e2 < CAP) orow[e2] = (unsigned short)((lane + 128) * 32 + bb); ++e2; m &= m - 1; }
}

// ---------------------------------------------------------------------------
// Gather-sum: agg[R,:] = sum_{j in list(R)} table[j,:]   (R = c*M + r)
// Table is 1.57 MB -> L2-resident. One wave per R; 4 gather-groups of 16
// lanes x float4 = one 256B row per group; 4x unroll -> 16 loads in flight.
// ---------------------------------------------------------------------------
__global__ __launch_bounds__(256) void k_gather(
    const int* __restrict__ cnt,             // [CM]
    const unsigned short* __restrict__ idx,  // [CM][CAP]
    const float* __restrict__ table,         // [N][64]
    float* __restrict__ agg) {               // [CM][64]
  __shared__ float4 red4[4][16];
  const int wave = threadIdx.x >> 6;
  const int lane = threadIdx.x & 63;
  const int R = blockIdx.x * 4 + wave;
  const int g    = lane >> 4;       // gather group 0..3
  const int e16  = lane & 15;       // 16B chunk of the 256B row
  int n = cnt[R];
  n = n > CAP ? CAP : n;
  const unsigned short* l = idx + (size_t)R * CAP;
  const float4* tab = (const float4*)table;
  float4 a0 = make_float4(0.f,0.f,0.f,0.f), a1 = a0, a2 = a0, a3 = a0;
  int i = 0;
  for (; i + 16 <= n; i += 16) {
    const int j0 = l[i + g], j1 = l[i + 4 + g];
    const int j2 = l[i + 8 + g], j3 = l[i + 12 + g];
    const float4 x0 = tab[j0 * 16 + e16];
    const float4 x1 = tab[j1 * 16 + e16];
    const float4 x2 = tab[j2 * 16 + e16];
    const float4 x3 = tab[j3 * 16 + e16];
    a0.x += x0.x; a0.y += x0.y; a0.z += x0.z; a0.w += x0.w;
    a1.x += x1.x; a1.y += x1.y; a1.z += x1.z; a1.w += x1.w;
    a2.x += x2.x; a2.y += x2.y; a2.z += x2.z; a2.w += x2.w;
    a3.x += x3.x; a3.y += x3.y; a3.z += x3.z; a3.w += x3.w;
  }
  for (; i + 4 <= n; i += 4) {
    const float4 x = tab[(int)l[i + g] * 16 + e16];
    a0.x += x.x; a0.y += x.y; a0.z += x.z; a0.w += x.w;
  }
  if (i + g < n) {
    const float4 x = tab[(int)l[i + g] * 16 + e16];
    a1.x += x.x; a1.y += x.y; a1.z += x.z; a1.w += x.w;
  }
  a0.x += a1.x + a2.x + a3.x;
  a0.y += a1.y + a2.y + a3.y;
  a0.z += a1.z + a2.z + a3.z;
  a0.w += a1.w + a2.w + a3.w;
  #pragma unroll
  for (int off = 16; off < 64; off <<= 1) {
    a0.x += __shfl_xor(a0.x, off, 64);
    a0.y += __shfl_xor(a0.y, off, 64);
    a0.z += __shfl_xor(a0.z, off, 64);
    a0.w += __shfl_xor(a0.w, off, 64);
  }
  if (g == 0) red4[wave][e16] = a0;
  __syncthreads();
  if (g == 0) ((float4*)agg)[(size_t)R * 16 + e16] = red4[wave][e16];
}

// ---------------------------------------------------------------------------
// Fused 5-class 64x64 GEMM: out[r,e] = act(sum_c sum_d agg[c,r,d]*W[c,d,e]
//                                          + sum_c bias[c,e])
// lane = e; W column cached in 64 VGPRs per class; 4 rows per wave.
// ---------------------------------------------------------------------------
__global__ __launch_bounds__(256) void k_gemm5(
    const float* __restrict__ agg,   // [C][M][64]
    const float* __restrict__ W,     // [C][64][64]
    const float* __restrict__ bias,  // [C][64]
    float* __restrict__ out,         // [M][64]
    int M, int do_relu) {
  const int lane = threadIdx.x & 63;
  const int wave = threadIdx.x >> 6;
  const int r0 = blockIdx.x * 16 + wave * 4;
  float bs = 0.0f;
  #pragma unroll
  for (int c = 0; c < NC; ++c) bs += bias[c * 64 + lane];
  float acc[4] = {bs, bs, bs, bs};
  for (int c = 0; c < NC; ++c) {
    float w[64];
    #pragma unroll
    for (int d = 0; d < 64; ++d) w[d] = W[c * 4096 + d * 64 + lane];
    #pragma unroll
    for (int r = 0; r < 4; ++r) {
      const float4* ar = (const float4*)(agg + ((size_t)c * M + r0 + r) * 64);
      #pragma unroll
      for (int d4 = 0; d4 < 16; ++d4) {
        const float4 a = ar[d4];
        acc[r] = fmaf(a.x, w[d4 * 4 + 0], acc[r]);
        acc[r] = fmaf(a.y, w[d4 * 4 + 1], acc[r]);
        acc[r] = fmaf(a.z, w[d4 * 4 + 2], acc[r]);
        acc[r] = fmaf(a.w, w[d4 * 4 + 3], acc[r]);
      }
    }
  }
  #pragma unroll
  for (int r = 0; r < 4; ++r) {
    const float x = do_relu ? fmaxf(acc[r], 0.0f) : acc[r];
    out[(size_t)(r0 + r) * 64 + lane] = x;
  }
}

// ---------------------------------------------------------------------------
// Decoder: logits[b,c] = sum_{d,e} z_u[u[b],d] * Q[c,d,e] * z_v[v[b],e]
// ---------------------------------------------------------------------------
__global__ __launch_bounds__(256) void k_decoder(
    const int* __restrict__ uu, const int* __restrict__ vv,
    const float* __restrict__ z_u, const float* __restrict__ z_v,
    const float* __restrict__ Q,   // C x 64 x 64
    float* __restrict__ out) {     // B x C
  const int lane = threadIdx.x & 63;
  const int wave = threadIdx.x >> 6;
  const int b = blockIdx.x * 4 + wave;
  const int ub = uu[b];
  const int vb = vv[b];
  const float zve = z_v[(size_t)vb * 64 + lane];
  const float* zu = z_u + (size_t)ub * 64;            // wave-uniform reads
  #pragma unroll
  for (int c = 0; c < NC; ++c) {
    const float* Qc = Q + c * 64 * 64;
    float t = 0.0f;
    #pragma unroll
    for (int d = 0; d < 64; ++d) t = fmaf(zu[d], Qc[d * 64 + lane], t);
    float p = t * zve;
    #pragma unroll
    for (int off = 32; off > 0; off >>= 1) p += __shfl_xor(p, off, 64);
    if (lane == 0) out[(size_t)b * NC + c] = p;
  }
}

extern "C" void kernel_launch(void* const* d_in, const int* in_sizes, int n_in,
                              void* d_out, int out_size, void* d_ws, size_t ws_size,
                              hipStream_t stream) {
  const int*   u     = (const int*)d_in[0];
  const int*   v     = (const int*)d_in[1];
  const float* u_emb = (const float*)d_in[2];
  const float* v_emb = (const float*)d_in[3];
  const float* W1u   = (const float*)d_in[4];
  const float* b1u   = (const float*)d_in[5];
  const float* W1v   = (const float*)d_in[6];
  const float* b1v   = (const float*)d_in[7];
  const float* W2u   = (const float*)d_in[8];
  const float* b2u   = (const float*)d_in[9];
  const float* W2v   = (const float*)d_in[10];
  const float* b2v   = (const float*)d_in[11];
  const float* Q     = (const float*)d_in[12];
  const float* adj   = (const float*)d_in[13];
  float* out = (float*)d_out;

  // ---- workspace carve-up ----
  char* ws = (char*)d_ws;
  int* csr_cnt = (int*)ws;                                   // 5*6144 ints
  int* csc_cnt = csr_cnt + NC * NU;                          //  (245,760 B)
  unsigned short* csr_idx = (unsigned short*)(ws + 245760);  // 7,864,320 B
  unsigned short* csc_idx = (unsigned short*)(ws + 245760 + 7864320);
  char* maskbase = ws + 245760 + 2 * 7864320;
  unsigned int* rowmask = (unsigned int*)maskbase;           // 23,592,960 B
  unsigned int* colmask = (unsigned int*)(maskbase + 23592960);
  // agg/h/z buffers alias the rowmask region (dead after k_expand):
  float* aggA = (float*)maskbase;                            // 7,864,320 B
  float* aggB = (float*)(maskbase + 7864320);                // 7,864,320 B
  float* h_u  = (float*)(maskbase + 15728640);               // 1,572,864 B
  float* h_v  = (float*)(maskbase + 17301504);
  float* z_u  = (float*)(maskbase + 18874368);
  float* z_v  = (float*)(maskbase + 20447232);               // ends 22,020,096

  // Pass 1: single coalesced read of dense adj -> row/col bitmasks
  k_bitmask<<<5 * 96 * 24, 256, 0, stream>>>(adj, rowmask, colmask);
  // Pass 2: bitmasks -> CSR / CSC (atomic-free)
  k_expand<<<NC * NU / 4, 256, 0, stream>>>(rowmask, csr_cnt, csr_idx);
  k_expand<<<NC * NV / 4, 256, 0, stream>>>(colmask, csc_cnt, csc_idx);

  // ---- layer 1: gather L2-resident embeddings, then tiny per-class GEMMs
  k_gather<<<NC * NU / 4, 256, 0, stream>>>(csr_cnt, csr_idx, v_emb, aggA);
  k_gather<<<NC * NV / 4, 256, 0, stream>>>(csc_cnt, csc_idx, u_emb, aggB);
  k_gemm5<<<NU / 16, 256, 0, stream>>>(aggA, W1v, b1v, h_u, NU, 1);
  k_gemm5<<<NV / 16, 256, 0, stream>>>(aggB, W1u, b1u, h_v, NV, 1);
  // ---- layer 2: same structure on h_v / h_u
  k_gather<<<NC * NU / 4, 256, 0, stream>>>(csr_cnt, csr_idx, h_v, aggA);
  k_gather<<<NC * NV / 4, 256, 0, stream>>>(csc_cnt, csc_idx, h_u, aggB);
  k_gemm5<<<NU / 16, 256, 0, stream>>>(aggA, W2u, b2u, z_u, NU, 0);
  k_gemm5<<<NV / 16, 256, 0, stream>>>(aggB, W2v, b2v, z_v, NV, 0);
  // ---- bilinear decoder
  k_decoder<<<NB / 4, 256, 0, stream>>>(u, v, z_u, z_v, Q, out);
}

// Round 4
// 1232.213 us; speedup vs baseline: 1.4203x; 1.0248x over previous
//
#include <hip/hip_runtime.h>

// Problem constants
#define NC   5
#define NU   6144
#define NV   6144
#define ND   64
#define NB   4096
#define CAP  128    // max nnz per row/col per class (mean 61.4, +8.5 sigma)
#define NW   192    // mask words per row (6144/32)
#define HALF (NC * NU)   // 30720 rows per side

// spread bits of a byte to every 4th bit of a u32
__device__ __forceinline__ unsigned int spread4(unsigned int x) {
  x &= 0xFFu;
  x = (x | (x << 12)) & 0x000F000Fu;
  x = (x | (x << 6))  & 0x03030303u;
  x = (x | (x << 3))  & 0x11111111u;
  return x;
}

// ---------------------------------------------------------------------------
// Pass 1: dense adj [C,U,V] fp32 (exactly 0/1) -> TRANSPOSED bitmasks:
//   maskT plane layout: [2*C*192 planes][6144 dims], dim contiguous.
//   row side: plane = c*192 + vword, dim = u
//   col side: plane = (C + c)*192 + uword, dim = v
// Tile = 64 u x 256 v. All global stores fully coalesced dwords.
// ---------------------------------------------------------------------------
__global__ __launch_bounds__(256) void k_bitmask(
    const float* __restrict__ adj,
    unsigned int* __restrict__ maskT) {
  __shared__ unsigned int rowwords[64][9];   // +1 pad: breaks 8-way conflicts
  const int b = blockIdx.x;                  // 5 * 96 * 24 tiles
  const int c  = b / 2304;
  const int rem = b - c * 2304;
  const int tu = rem / 24;
  const int tv = rem - tu * 24;
  const int wave = threadIdx.x >> 6;
  const int lane = threadIdx.x & 63;

  // ---- row phase: preload 16 rows (16 loads in flight), ballot-pack ----
  float4 av[16];
  {
    const float* base = adj +
        ((size_t)(c * NU + tu * 64 + wave * 16) * NV + tv * 256);
    #pragma unroll
    for (int rr = 0; rr < 16; ++rr)
      av[rr] = ((const float4*)(base + (size_t)rr * NV))[lane];
  }
  #pragma unroll
  for (int rr = 0; rr < 16; ++rr) {
    const unsigned long long b0 = __ballot(av[rr].x != 0.0f);
    const unsigned long long b1 = __ballot(av[rr].y != 0.0f);
    const unsigned long long b2 = __ballot(av[rr].z != 0.0f);
    const unsigned long long b3 = __ballot(av[rr].w != 0.0f);
    if (lane < 8) {                    // word w = lane covers lanes w*8..w*8+7
      const unsigned int e0 = spread4((unsigned int)(b0 >> (lane * 8)));
      const unsigned int e1 = spread4((unsigned int)(b1 >> (lane * 8)));
      const unsigned int e2 = spread4((unsigned int)(b2 >> (lane * 8)));
      const unsigned int e3 = spread4((unsigned int)(b3 >> (lane * 8)));
      rowwords[wave * 16 + rr][lane] = e0 | (e1 << 1) | (e2 << 2) | (e3 << 3);
    }
  }
  __syncthreads();

  // ---- row-side store: plane (c*192 + tv*8 + k), dims tu*64 + r ----
  {
    const int k  = threadIdx.x >> 5;   // vword 0..7
    const int rb = threadIdx.x & 31;   // row 0..31
    unsigned int* p = maskT + ((size_t)c * 192 + tv * 8 + k) * 6144 + tu * 64;
    p[rb]      = rowwords[rb][k];      // coalesced 128B per 32-lane group
    p[rb + 32] = rowwords[rb + 32][k];
  }

  // ---- col-side: bit-transpose in registers, coalesced store ----
  {
    const int j = threadIdx.x;         // local col 0..255
    const int w = j >> 5, bit = j & 31;
    unsigned int w0 = 0, w1 = 0;
    #pragma unroll
    for (int r = 0; r < 32; ++r) {
      w0 |= ((rowwords[r][w]      >> bit) & 1u) << r;   // broadcast reads
      w1 |= ((rowwords[r + 32][w] >> bit) & 1u) << r;
    }
    unsigned int* p = maskT +
        ((size_t)(NC + c) * 192 + tu * 2) * 6144 + tv * 256 + j;
    p[0]    = w0;                      // coalesced 1KB per 256 threads
    p[6144] = w1;
  }
}

// ---------------------------------------------------------------------------
// Pass 2: transposed mask -> per-row index list + count. Lane owns one dim's
// full 192-word row; loads coalesced across lanes; 16-word register batches
// for ILP; running offset per lane (no prefix sums, no atomics).
// Covers BOTH sides in one launch: 960 waves total.
// ---------------------------------------------------------------------------
__global__ __launch_bounds__(256) void k_expand(
    const unsigned int* __restrict__ maskT,
    int* __restrict__ cnt,                  // [2*C*6144]
    unsigned short* __restrict__ idx) {     // [2*C*6144][CAP]
  const int wv = blockIdx.x * 4 + (threadIdx.x >> 6);  // 0..959
  const int lane = threadIdx.x & 63;
  const int sc = wv / 96;                  // side*C + c  (0..9)
  const int g  = wv - sc * 96;             // dim group
  const int dim = g * 64 + lane;
  const unsigned int* base = maskT + (size_t)sc * 192 * 6144 + dim;
  const int R = sc * 6144 + dim;
  unsigned short* orow = idx + (size_t)R * CAP;
  int cur = 0;
  for (int wb = 0; wb < NW; wb += 16) {
    unsigned int wreg[16];
    #pragma unroll
    for (int t = 0; t < 16; ++t)
      wreg[t] = base[(size_t)(wb + t) * 6144];   // coalesced 256B
    #pragma unroll
    for (int t = 0; t < 16; ++t) {
      unsigned int m = wreg[t];
      const int wbase = (wb + t) * 32;
      while (m) {
        const int bb = __ffs(m) - 1;
        if (cur < CAP) orow[cur] = (unsigned short)(wbase + bb);
        ++cur;
        m &= m - 1;
      }
    }
  }
  cnt[R] = cur < CAP ? cur : CAP;
}

// ---------------------------------------------------------------------------
// Gather-sum, both sides in one launch:
//   R < HALF  : agg[R] = sum_{j} tabA[j]   (csr side)
//   R >= HALF : agg[R] = sum_{j} tabB[j]   (csc side)
// Tables are 1.57 MB -> L2-resident. One wave per R; 4 gather-groups of 16
// lanes x float4 = one 256B row per group; 4x unroll -> 16 loads in flight.
// ---------------------------------------------------------------------------
__global__ __launch_bounds__(256) void k_gather(
    const int* __restrict__ cnt,             // [2*HALF]
    const unsigned short* __restrict__ idx,  // [2*HALF][CAP]
    const float* __restrict__ tabA,          // [6144][64]
    const float* __restrict__ tabB,          // [6144][64]
    float* __restrict__ agg) {               // [2*HALF][64]
  __shared__ float4 red4[4][16];
  const int wave = threadIdx.x >> 6;
  const int lane = threadIdx.x & 63;
  const int R = blockIdx.x * 4 + wave;
  const int g    = lane >> 4;
  const int e16  = lane & 15;
  int n = cnt[R];
  n = n > CAP ? CAP : n;
  const unsigned short* l = idx + (size_t)R * CAP;
  const float4* tab = (const float4*)(R < HALF ? tabA : tabB);
  float4 a0 = make_float4(0.f,0.f,0.f,0.f), a1 = a0, a2 = a0, a3 = a0;
  int i = 0;
  for (; i + 16 <= n; i += 16) {
    const int j0 = l[i + g], j1 = l[i + 4 + g];
    const int j2 = l[i + 8 + g], j3 = l[i + 12 + g];
    const float4 x0 = tab[j0 * 16 + e16];
    const float4 x1 = tab[j1 * 16 + e16];
    const float4 x2 = tab[j2 * 16 + e16];
    const float4 x3 = tab[j3 * 16 + e16];
    a0.x += x0.x; a0.y += x0.y; a0.z += x0.z; a0.w += x0.w;
    a1.x += x1.x; a1.y += x1.y; a1.z += x1.z; a1.w += x1.w;
    a2.x += x2.x; a2.y += x2.y; a2.z += x2.z; a2.w += x2.w;
    a3.x += x3.x; a3.y += x3.y; a3.z += x3.z; a3.w += x3.w;
  }
  for (; i + 4 <= n; i += 4) {
    const float4 x = tab[(int)l[i + g] * 16 + e16];
    a0.x += x.x; a0.y += x.y; a0.z += x.z; a0.w += x.w;
  }
  if (i + g < n) {
    const float4 x = tab[(int)l[i + g] * 16 + e16];
    a1.x += x.x; a1.y += x.y; a1.z += x.z; a1.w += x.w;
  }
  a0.x += a1.x + a2.x + a3.x;
  a0.y += a1.y + a2.y + a3.y;
  a0.z += a1.z + a2.z + a3.z;
  a0.w += a1.w + a2.w + a3.w;
  #pragma unroll
  for (int off = 16; off < 64; off <<= 1) {
    a0.x += __shfl_xor(a0.x, off, 64);
    a0.y += __shfl_xor(a0.y, off, 64);
    a0.z += __shfl_xor(a0.z, off, 64);
    a0.w += __shfl_xor(a0.w, off, 64);
  }
  if (g == 0) red4[wave][e16] = a0;
  __syncthreads();
  if (g == 0) ((float4*)agg)[(size_t)R * 16 + e16] = red4[wave][e16];
}

// ---------------------------------------------------------------------------
// Fused 5-class 64x64 GEMM over both halves:
//   half 0: outA[r,e] = act(sum_c sum_d agg[c,r,d]*Wa[c,d,e] + sum_c ba[c,e])
//   half 1: same with agg second half / Wb / bb / outB.
// ---------------------------------------------------------------------------
__global__ __launch_bounds__(256) void k_gemm5(
    const float* __restrict__ agg,   // [2][C][6144][64]
    const float* __restrict__ Wa, const float* __restrict__ ba,
    float* __restrict__ outA,
    const float* __restrict__ Wb, const float* __restrict__ bb,
    float* __restrict__ outB,
    int do_relu) {
  const int half = blockIdx.x >= 384;
  const float* W    = half ? Wb : Wa;
  const float* bias = half ? bb : ba;
  float* out        = half ? outB : outA;
  const float* aggh = agg + (size_t)half * HALF * 64;
  const int lane = threadIdx.x & 63;
  const int wave = threadIdx.x >> 6;
  const int r0 = (blockIdx.x - half * 384) * 16 + wave * 4;
  float bs = 0.0f;
  #pragma unroll
  for (int c = 0; c < NC; ++c) bs += bias[c * 64 + lane];
  float acc[4] = {bs, bs, bs, bs};
  for (int c = 0; c < NC; ++c) {
    float w[64];
    #pragma unroll
    for (int d = 0; d < 64; ++d) w[d] = W[c * 4096 + d * 64 + lane];
    #pragma unroll
    for (int r = 0; r < 4; ++r) {
      const float4* ar = (const float4*)(aggh + ((size_t)c * 6144 + r0 + r) * 64);
      #pragma unroll
      for (int d4 = 0; d4 < 16; ++d4) {
        const float4 a = ar[d4];
        acc[r] = fmaf(a.x, w[d4 * 4 + 0], acc[r]);
        acc[r] = fmaf(a.y, w[d4 * 4 + 1], acc[r]);
        acc[r] = fmaf(a.z, w[d4 * 4 + 2], acc[r]);
        acc[r] = fmaf(a.w, w[d4 * 4 + 3], acc[r]);
      }
    }
  }
  #pragma unroll
  for (int r = 0; r < 4; ++r) {
    const float x = do_relu ? fmaxf(acc[r], 0.0f) : acc[r];
    out[(size_t)(r0 + r) * 64 + lane] = x;
  }
}

// ---------------------------------------------------------------------------
// Decoder: logits[b,c] = sum_{d,e} z_u[u[b],d] * Q[c,d,e] * z_v[v[b],e]
// ---------------------------------------------------------------------------
__global__ __launch_bounds__(256) void k_decoder(
    const int* __restrict__ uu, const int* __restrict__ vv,
    const float* __restrict__ z_u, const float* __restrict__ z_v,
    const float* __restrict__ Q,   // C x 64 x 64
    float* __restrict__ out) {     // B x C
  const int lane = threadIdx.x & 63;
  const int wave = threadIdx.x >> 6;
  const int b = blockIdx.x * 4 + wave;
  const int ub = uu[b];
  const int vb = vv[b];
  const float zve = z_v[(size_t)vb * 64 + lane];
  const float* zu = z_u + (size_t)ub * 64;            // wave-uniform reads
  #pragma unroll
  for (int c = 0; c < NC; ++c) {
    const float* Qc = Q + c * 64 * 64;
    float t = 0.0f;
    #pragma unroll
    for (int d = 0; d < 64; ++d) t = fmaf(zu[d], Qc[d * 64 + lane], t);
    float p = t * zve;
    #pragma unroll
    for (int off = 32; off > 0; off >>= 1) p += __shfl_xor(p, off, 64);
    if (lane == 0) out[(size_t)b * NC + c] = p;
  }
}

extern "C" void kernel_launch(void* const* d_in, const int* in_sizes, int n_in,
                              void* d_out, int out_size, void* d_ws, size_t ws_size,
                              hipStream_t stream) {
  const int*   u     = (const int*)d_in[0];
  const int*   v     = (const int*)d_in[1];
  const float* u_emb = (const float*)d_in[2];
  const float* v_emb = (const float*)d_in[3];
  const float* W1u   = (const float*)d_in[4];
  const float* b1u   = (const float*)d_in[5];
  const float* W1v   = (const float*)d_in[6];
  const float* b1v   = (const float*)d_in[7];
  const float* W2u   = (const float*)d_in[8];
  const float* b2u   = (const float*)d_in[9];
  const float* W2v   = (const float*)d_in[10];
  const float* b2v   = (const float*)d_in[11];
  const float* Q     = (const float*)d_in[12];
  const float* adj   = (const float*)d_in[13];
  float* out = (float*)d_out;

  // ---- workspace carve-up ----
  char* ws = (char*)d_ws;
  int* cnt = (int*)ws;                                       //   245,760 B
  unsigned short* idxL = (unsigned short*)(ws + 245760);     // 15,728,640 B
  char* maskbase = ws + 245760 + 15728640;
  unsigned int* maskT = (unsigned int*)maskbase;             // 47,185,920 B
  // agg/h/z alias the maskT region (masks dead after k_expand):
  float* agg = (float*)maskbase;                             // 15,728,640 B
  float* h_u = (float*)(maskbase + 15728640);
  float* h_v = (float*)(maskbase + 17301504);
  float* z_u = (float*)(maskbase + 18874368);
  float* z_v = (float*)(maskbase + 20447232);                // ends 22 MB

  // Pass 1: one coalesced read of adj -> transposed row/col bitmasks
  k_bitmask<<<NC * 96 * 24, 256, 0, stream>>>(adj, maskT);
  // Pass 2: masks -> CSR+CSC index lists (both sides, one launch)
  k_expand<<<240, 256, 0, stream>>>(maskT, cnt, idxL);

  // ---- layer 1: gather L2-resident embeddings, then per-class GEMMs
  k_gather<<<2 * HALF / 4, 256, 0, stream>>>(cnt, idxL, v_emb, u_emb, agg);
  k_gemm5<<<768, 256, 0, stream>>>(agg, W1v, b1v, h_u, W1u, b1u, h_v, 1);
  // ---- layer 2
  k_gather<<<2 * HALF / 4, 256, 0, stream>>>(cnt, idxL, h_v, h_u, agg);
  k_gemm5<<<768, 256, 0, stream>>>(agg, W2u, b2u, z_u, W2v, b2v, z_v, 0);
  // ---- bilinear decoder
  k_decoder<<<NB / 4, 256, 0, stream>>>(u, v, z_u, z_v, Q, out);
}

// Round 5
// 1171.401 us; speedup vs baseline: 1.4941x; 1.0519x over previous
//
#include <hip/hip_runtime.h>

// Problem constants
#define NC   5
#define NU   6144
#define NV   6144
#define ND   64
#define NB   4096
#define CAP  128     // max nnz per row/col per class (mean 61.4, +8.5 sigma)
#define HALF (NC * NU)   // 30720 rows per side

// spread bits of a byte to every 4th bit of a u32
__device__ __forceinline__ unsigned int spread4(unsigned int x) {
  x &= 0xFFu;
  x = (x | (x << 12)) & 0x000F000Fu;
  x = (x | (x << 6))  & 0x03030303u;
  x = (x | (x << 3))  & 0x11111111u;
  return x;
}

// ---------------------------------------------------------------------------
// One pass: dense adj [C,U,V] fp32 (exactly 0/1) -> CSR + CSC index lists
// directly. Tile = 64 u x 256 v per block. Ballot-pack rows into LDS words,
// then (a) row-side: 8 rows x 8 words per wave-pass, 8-lane prefix + one
// atomicAdd per row-tile reserves slots, lanes scatter indices;
// (b) col-side: register bit-transpose, one atomicAdd per nonempty column.
// Index order within a list is nondeterministic -- only permutes fp sums.
// ---------------------------------------------------------------------------
__global__ __launch_bounds__(256) void k_adj2idx(
    const float* __restrict__ adj,
    int* __restrict__ cnt,                // [2*C*6144] (csr | csc)
    unsigned short* __restrict__ idx) {   // [2*C*6144][CAP]
  __shared__ unsigned int rowwords[64][9];   // +1 pad
  const int b = blockIdx.x;                  // 5 * 96 * 24 tiles
  const int c  = b / 2304;
  const int rem = b - c * 2304;
  const int tu = rem / 24;
  const int tv = rem - tu * 24;
  const int wave = threadIdx.x >> 6;
  const int lane = threadIdx.x & 63;

  // ---- load + ballot-pack 16 rows per wave ----
  float4 av[16];
  {
    const float* base = adj +
        ((size_t)(c * NU + tu * 64 + wave * 16) * NV + tv * 256);
    #pragma unroll
    for (int rr = 0; rr < 16; ++rr)
      av[rr] = ((const float4*)(base + (size_t)rr * NV))[lane];
  }
  #pragma unroll
  for (int rr = 0; rr < 16; ++rr) {
    const unsigned long long b0 = __ballot(av[rr].x != 0.0f);
    const unsigned long long b1 = __ballot(av[rr].y != 0.0f);
    const unsigned long long b2 = __ballot(av[rr].z != 0.0f);
    const unsigned long long b3 = __ballot(av[rr].w != 0.0f);
    if (lane < 8) {                    // word w = lane covers lanes w*8..w*8+7
      const unsigned int e0 = spread4((unsigned int)(b0 >> (lane * 8)));
      const unsigned int e1 = spread4((unsigned int)(b1 >> (lane * 8)));
      const unsigned int e2 = spread4((unsigned int)(b2 >> (lane * 8)));
      const unsigned int e3 = spread4((unsigned int)(b3 >> (lane * 8)));
      rowwords[wave * 16 + rr][lane] = e0 | (e1 << 1) | (e2 << 2) | (e3 << 3);
    }
  }
  __syncthreads();

  // ---- row side: 2 passes of 8 rows x 8 words per wave ----
  #pragma unroll
  for (int p = 0; p < 2; ++p) {
    const int rloc = lane >> 3;        // row within pass (0..7)
    const int wloc = lane & 7;         // word (0..7)
    const int r = wave * 16 + p * 8 + rloc;          // tile row 0..63
    const unsigned int wbits = rowwords[r][wloc];
    const int pc = __popc(wbits);
    int pre = pc;                      // inclusive prefix within 8-lane group
    #pragma unroll
    for (int d = 1; d < 8; d <<= 1) {
      const int y = __shfl_up(pre, d, 64);
      if (wloc >= d) pre += y;
    }
    const int total = __shfl(pre, rloc * 8 + 7, 64);
    const int excl  = pre - pc;
    const int R = c * 6144 + tu * 64 + r;            // csr row id
    int base = 0;
    if (wloc == 0 && total > 0) base = atomicAdd(&cnt[R], total);
    base = __shfl(base, rloc * 8, 64);
    unsigned int m = wbits;
    int o = base + excl;
    unsigned short* orow = idx + (size_t)R * CAP;
    const int vbase = tv * 256 + wloc * 32;
    while (m) {
      const int bb = __ffs(m) - 1;
      if (o < CAP) orow[o] = (unsigned short)(vbase + bb);
      ++o;
      m &= m - 1;
    }
  }

  // ---- col side: bit-transpose in registers, one atomic per nonempty col --
  {
    const int j = threadIdx.x;         // local col 0..255
    const int w = j >> 5, bit = j & 31;
    unsigned int w0 = 0, w1 = 0;
    #pragma unroll
    for (int r = 0; r < 32; ++r) {
      w0 |= ((rowwords[r][w]      >> bit) & 1u) << r;   // broadcast reads
      w1 |= ((rowwords[r + 32][w] >> bit) & 1u) << r;
    }
    const int cj = __popc(w0) + __popc(w1);
    if (cj > 0) {
      const int R = (NC + c) * 6144 + tv * 256 + j;    // csc row id
      int o = atomicAdd(&cnt[R], cj);
      unsigned short* orow = idx + (size_t)R * CAP;
      const int ubase = tu * 64;
      unsigned int m = w0;
      while (m) {
        const int bb = __ffs(m) - 1;
        if (o < CAP) orow[o] = (unsigned short)(ubase + bb);
        ++o;
        m &= m - 1;
      }
      m = w1;
      while (m) {
        const int bb = __ffs(m) - 1;
        if (o < CAP) orow[o] = (unsigned short)(ubase + 32 + bb);
        ++o;
        m &= m - 1;
      }
    }
  }
}

// ---------------------------------------------------------------------------
// Gather-sum, both sides in one launch:
//   R < HALF  : agg[R] = sum_{j} tabA[j]   (csr side)
//   R >= HALF : agg[R] = sum_{j} tabB[j]   (csc side)
// Tables are 1.57 MB -> L2-resident. One wave per R; 4 gather-groups of 16
// lanes x float4 = one 256B row per group; 4x unroll -> 16 loads in flight.
// ---------------------------------------------------------------------------
__global__ __launch_bounds__(256) void k_gather(
    const int* __restrict__ cnt,             // [2*HALF]
    const unsigned short* __restrict__ idx,  // [2*HALF][CAP]
    const float* __restrict__ tabA,          // [6144][64]
    const float* __restrict__ tabB,          // [6144][64]
    float* __restrict__ agg) {               // [2*HALF][64]
  __shared__ float4 red4[4][16];
  const int wave = threadIdx.x >> 6;
  const int lane = threadIdx.x & 63;
  const int R = blockIdx.x * 4 + wave;
  const int g    = lane >> 4;
  const int e16  = lane & 15;
  int n = cnt[R];
  n = n > CAP ? CAP : n;
  const unsigned short* l = idx + (size_t)R * CAP;
  const float4* tab = (const float4*)(R < HALF ? tabA : tabB);
  float4 a0 = make_float4(0.f,0.f,0.f,0.f), a1 = a0, a2 = a0, a3 = a0;
  int i = 0;
  for (; i + 16 <= n; i += 16) {
    const int j0 = l[i + g], j1 = l[i + 4 + g];
    const int j2 = l[i + 8 + g], j3 = l[i + 12 + g];
    const float4 x0 = tab[j0 * 16 + e16];
    const float4 x1 = tab[j1 * 16 + e16];
    const float4 x2 = tab[j2 * 16 + e16];
    const float4 x3 = tab[j3 * 16 + e16];
    a0.x += x0.x; a0.y += x0.y; a0.z += x0.z; a0.w += x0.w;
    a1.x += x1.x; a1.y += x1.y; a1.z += x1.z; a1.w += x1.w;
    a2.x += x2.x; a2.y += x2.y; a2.z += x2.z; a2.w += x2.w;
    a3.x += x3.x; a3.y += x3.y; a3.z += x3.z; a3.w += x3.w;
  }
  for (; i + 4 <= n; i += 4) {
    const float4 x = tab[(int)l[i + g] * 16 + e16];
    a0.x += x.x; a0.y += x.y; a0.z += x.z; a0.w += x.w;
  }
  if (i + g < n) {
    const float4 x = tab[(int)l[i + g] * 16 + e16];
    a1.x += x.x; a1.y += x.y; a1.z += x.z; a1.w += x.w;
  }
  a0.x += a1.x + a2.x + a3.x;
  a0.y += a1.y + a2.y + a3.y;
  a0.z += a1.z + a2.z + a3.z;
  a0.w += a1.w + a2.w + a3.w;
  #pragma unroll
  for (int off = 16; off < 64; off <<= 1) {
    a0.x += __shfl_xor(a0.x, off, 64);
    a0.y += __shfl_xor(a0.y, off, 64);
    a0.z += __shfl_xor(a0.z, off, 64);
    a0.w += __shfl_xor(a0.w, off, 64);
  }
  if (g == 0) red4[wave][e16] = a0;
  __syncthreads();
  if (g == 0) ((float4*)agg)[(size_t)R * 16 + e16] = red4[wave][e16];
}

// ---------------------------------------------------------------------------
// Fused 5-class 64x64 GEMM over both halves:
//   half 0: outA[r,e] = act(sum_c sum_d agg[c,r,d]*Wa[c,d,e] + sum_c ba[c,e])
//   half 1: same with agg second half / Wb / bb / outB.
// ---------------------------------------------------------------------------
__global__ __launch_bounds__(256) void k_gemm5(
    const float* __restrict__ agg,   // [2][C][6144][64]
    const float* __restrict__ Wa, const float* __restrict__ ba,
    float* __restrict__ outA,
    const float* __restrict__ Wb, const float* __restrict__ bb,
    float* __restrict__ outB,
    int do_relu) {
  const int half = blockIdx.x >= 384;
  const float* W    = half ? Wb : Wa;
  const float* bias = half ? bb : ba;
  float* out        = half ? outB : outA;
  const float* aggh = agg + (size_t)half * HALF * 64;
  const int lane = threadIdx.x & 63;
  const int wave = threadIdx.x >> 6;
  const int r0 = (blockIdx.x - half * 384) * 16 + wave * 4;
  float bs = 0.0f;
  #pragma unroll
  for (int c = 0; c < NC; ++c) bs += bias[c * 64 + lane];
  float acc[4] = {bs, bs, bs, bs};
  for (int c = 0; c < NC; ++c) {
    float w[64];
    #pragma unroll
    for (int d = 0; d < 64; ++d) w[d] = W[c * 4096 + d * 64 + lane];
    #pragma unroll
    for (int r = 0; r < 4; ++r) {
      const float4* ar = (const float4*)(aggh + ((size_t)c * 6144 + r0 + r) * 64);
      #pragma unroll
      for (int d4 = 0; d4 < 16; ++d4) {
        const float4 a = ar[d4];
        acc[r] = fmaf(a.x, w[d4 * 4 + 0], acc[r]);
        acc[r] = fmaf(a.y, w[d4 * 4 + 1], acc[r]);
        acc[r] = fmaf(a.z, w[d4 * 4 + 2], acc[r]);
        acc[r] = fmaf(a.w, w[d4 * 4 + 3], acc[r]);
      }
    }
  }
  #pragma unroll
  for (int r = 0; r < 4; ++r) {
    const float x = do_relu ? fmaxf(acc[r], 0.0f) : acc[r];
    out[(size_t)(r0 + r) * 64 + lane] = x;
  }
}

// ---------------------------------------------------------------------------
// Decoder: logits[b,c] = sum_{d,e} z_u[u[b],d] * Q[c,d,e] * z_v[v[b],e]
// ---------------------------------------------------------------------------
__global__ __launch_bounds__(256) void k_decoder(
    const int* __restrict__ uu, const int* __restrict__ vv,
    const float* __restrict__ z_u, const float* __restrict__ z_v,
    const float* __restrict__ Q,   // C x 64 x 64
    float* __restrict__ out) {     // B x C
  const int lane = threadIdx.x & 63;
  const int wave = threadIdx.x >> 6;
  const int b = blockIdx.x * 4 + wave;
  const int ub = uu[b];
  const int vb = vv[b];
  const float zve = z_v[(size_t)vb * 64 + lane];
  const float* zu = z_u + (size_t)ub * 64;            // wave-uniform reads
  #pragma unroll
  for (int c = 0; c < NC; ++c) {
    const float* Qc = Q + c * 64 * 64;
    float t = 0.0f;
    #pragma unroll
    for (int d = 0; d < 64; ++d) t = fmaf(zu[d], Qc[d * 64 + lane], t);
    float p = t * zve;
    #pragma unroll
    for (int off = 32; off > 0; off >>= 1) p += __shfl_xor(p, off, 64);
    if (lane == 0) out[(size_t)b * NC + c] = p;
  }
}

extern "C" void kernel_launch(void* const* d_in, const int* in_sizes, int n_in,
                              void* d_out, int out_size, void* d_ws, size_t ws_size,
                              hipStream_t stream) {
  const int*   u     = (const int*)d_in[0];
  const int*   v     = (const int*)d_in[1];
  const float* u_emb = (const float*)d_in[2];
  const float* v_emb = (const float*)d_in[3];
  const float* W1u   = (const float*)d_in[4];
  const float* b1u   = (const float*)d_in[5];
  const float* W1v   = (const float*)d_in[6];
  const float* b1v   = (const float*)d_in[7];
  const float* W2u   = (const float*)d_in[8];
  const float* b2u   = (const float*)d_in[9];
  const float* W2v   = (const float*)d_in[10];
  const float* b2v   = (const float*)d_in[11];
  const float* Q     = (const float*)d_in[12];
  const float* adj   = (const float*)d_in[13];
  float* out = (float*)d_out;

  // ---- workspace carve-up (~38 MB) ----
  char* ws = (char*)d_ws;
  int* cnt = (int*)ws;                                       //   245,760 B
  unsigned short* idxL = (unsigned short*)(ws + 245760);     // 15,728,640 B
  char* fbase = ws + 245760 + 15728640;
  float* agg = (float*)fbase;                                // 15,728,640 B
  float* h_u = (float*)(fbase + 15728640);
  float* h_v = (float*)(fbase + 17301504);
  float* z_u = (float*)(fbase + 18874368);
  float* z_v = (float*)(fbase + 20447232);                   // ends ~22 MB

  // zero the counters (ws is poisoned 0xAA each call)
  hipMemsetAsync(cnt, 0, 2 * NC * 6144 * sizeof(int), stream);

  // One pass over adj -> CSR + CSC index lists (no masks, no expand pass)
  k_adj2idx<<<NC * 96 * 24, 256, 0, stream>>>(adj, cnt, idxL);

  // ---- layer 1: gather L2-resident embeddings, then per-class GEMMs
  k_gather<<<2 * HALF / 4, 256, 0, stream>>>(cnt, idxL, v_emb, u_emb, agg);
  k_gemm5<<<768, 256, 0, stream>>>(agg, W1v, b1v, h_u, W1u, b1u, h_v, 1);
  // ---- layer 2
  k_gather<<<2 * HALF / 4, 256, 0, stream>>>(cnt, idxL, h_v, h_u, agg);
  k_gemm5<<<768, 256, 0, stream>>>(agg, W2u, b2u, z_u, W2v, b2v, z_v, 0);
  // ---- bilinear decoder
  k_decoder<<<NB / 4, 256, 0, stream>>>(u, v, z_u, z_v, Q, out);
}

// Round 6
// 1164.648 us; speedup vs baseline: 1.5027x; 1.0058x over previous
//
#include <hip/hip_runtime.h>

// Problem constants
#define NC   5
#define NU   6144
#define NV   6144
#define ND   64
#define NB   4096
#define CAP  128     // max nnz per row/col per class (mean 61.4, +8.5 sigma)
#define HALF (NC * NU)   // 30720 rows per side

// spread bits of a byte to every 4th bit of a u32
__device__ __forceinline__ unsigned int spread4(unsigned int x) {
  x &= 0xFFu;
  x = (x | (x << 12)) & 0x000F000Fu;
  x = (x | (x << 6))  & 0x03030303u;
  x = (x | (x << 3))  & 0x11111111u;
  return x;
}

// ---------------------------------------------------------------------------
// One pass: dense adj [C,U,V] fp32 (exactly 0/1) -> CSR + CSC index lists.
// Tile = 64 u x 256 v per block. blockIdx is XCD-swizzled so all 24 tv-tiles
// of one (c,tu) row-stripe run on the same XCD (blockIdx%8 == XCD heuristic):
// row-side cnt/idx lines stay XCD-local -> no cross-die ping-pong on the
// atomics + u16 scatter stores. (Col side remains cross-XCD; unavoidable
// with a single pass.)
// ---------------------------------------------------------------------------
__global__ __launch_bounds__(256) void k_adj2idx(
    const float* __restrict__ adj,
    int* __restrict__ cnt,                // [2*C*6144] (csr | csc)
    unsigned short* __restrict__ idx) {   // [2*C*6144][CAP]
  __shared__ unsigned int rowwords[64][9];   // +1 pad
  // ---- swizzled tile decode: stripe S=(c*96+tu) pinned to XCD S%8 ----
  const int x = blockIdx.x & 7;
  const int s = blockIdx.x >> 3;             // 0..1439
  const int tv = s % 24;
  const int S = (s / 24) * 8 + x;            // 0..479
  const int c  = S / 96;
  const int tu = S - c * 96;
  const int wave = threadIdx.x >> 6;
  const int lane = threadIdx.x & 63;

  // ---- load + ballot-pack 16 rows per wave ----
  float4 av[16];
  {
    const float* base = adj +
        ((size_t)(c * NU + tu * 64 + wave * 16) * NV + tv * 256);
    #pragma unroll
    for (int rr = 0; rr < 16; ++rr)
      av[rr] = ((const float4*)(base + (size_t)rr * NV))[lane];
  }
  #pragma unroll
  for (int rr = 0; rr < 16; ++rr) {
    const unsigned long long b0 = __ballot(av[rr].x != 0.0f);
    const unsigned long long b1 = __ballot(av[rr].y != 0.0f);
    const unsigned long long b2 = __ballot(av[rr].z != 0.0f);
    const unsigned long long b3 = __ballot(av[rr].w != 0.0f);
    if (lane < 8) {                    // word w = lane covers lanes w*8..w*8+7
      const unsigned int e0 = spread4((unsigned int)(b0 >> (lane * 8)));
      const unsigned int e1 = spread4((unsigned int)(b1 >> (lane * 8)));
      const unsigned int e2 = spread4((unsigned int)(b2 >> (lane * 8)));
      const unsigned int e3 = spread4((unsigned int)(b3 >> (lane * 8)));
      rowwords[wave * 16 + rr][lane] = e0 | (e1 << 1) | (e2 << 2) | (e3 << 3);
    }
  }
  __syncthreads();

  // ---- row side: 2 passes of 8 rows x 8 words per wave ----
  #pragma unroll
  for (int p = 0; p < 2; ++p) {
    const int rloc = lane >> 3;        // row within pass (0..7)
    const int wloc = lane & 7;         // word (0..7)
    const int r = wave * 16 + p * 8 + rloc;          // tile row 0..63
    const unsigned int wbits = rowwords[r][wloc];
    const int pc = __popc(wbits);
    int pre = pc;                      // inclusive prefix within 8-lane group
    #pragma unroll
    for (int d = 1; d < 8; d <<= 1) {
      const int y = __shfl_up(pre, d, 64);
      if (wloc >= d) pre += y;
    }
    const int total = __shfl(pre, rloc * 8 + 7, 64);
    const int excl  = pre - pc;
    const int R = c * 6144 + tu * 64 + r;            // csr row id
    int base = 0;
    if (wloc == 0 && total > 0) base = atomicAdd(&cnt[R], total);
    base = __shfl(base, rloc * 8, 64);
    unsigned int m = wbits;
    int o = base + excl;
    unsigned short* orow = idx + (size_t)R * CAP;
    const int vbase = tv * 256 + wloc * 32;
    while (m) {
      const int bb = __ffs(m) - 1;
      if (o < CAP) orow[o] = (unsigned short)(vbase + bb);
      ++o;
      m &= m - 1;
    }
  }

  // ---- col side: bit-transpose in registers, one atomic per nonempty col --
  {
    const int j = threadIdx.x;         // local col 0..255
    const int w = j >> 5, bit = j & 31;
    unsigned int w0 = 0, w1 = 0;
    #pragma unroll
    for (int r = 0; r < 32; ++r) {
      w0 |= ((rowwords[r][w]      >> bit) & 1u) << r;   // broadcast reads
      w1 |= ((rowwords[r + 32][w] >> bit) & 1u) << r;
    }
    const int cj = __popc(w0) + __popc(w1);
    if (cj > 0) {
      const int R = (NC + c) * 6144 + tv * 256 + j;    // csc row id
      int o = atomicAdd(&cnt[R], cj);
      unsigned short* orow = idx + (size_t)R * CAP;
      const int ubase = tu * 64;
      unsigned int m = w0;
      while (m) {
        const int bb = __ffs(m) - 1;
        if (o < CAP) orow[o] = (unsigned short)(ubase + bb);
        ++o;
        m &= m - 1;
      }
      m = w1;
      while (m) {
        const int bb = __ffs(m) - 1;
        if (o < CAP) orow[o] = (unsigned short)(ubase + 32 + bb);
        ++o;
        m &= m - 1;
      }
    }
  }
}

// ---------------------------------------------------------------------------
// Fused layer: gather (5 classes x 16 rows -> LDS) + 5-class 64x64 GEMM.
//   blocks 0..383  : side A rows r0=blk*16       (gathers tabA, W=Wa, out=outA)
//   blocks 384..767: side B rows r0=(blk-384)*16 (gathers tabB, W=Wb, out=outB)
// Gather phase: wave w owns rows [w*4, w*4+4), all 5 classes; per (c,r):
// 4 gather-groups of 16 lanes x float4 (one 256B table row per group),
// 4x unroll -> 16 loads in flight; xor-shuffle group reduce; 256B agg -> LDS.
// GEMM phase (after one __syncthreads): identical to old k_gemm5, W column
// in 64 VGPRs per class (amortized over 16 rows), agg read from LDS broadcast.
// ---------------------------------------------------------------------------
__global__ __launch_bounds__(256) void k_layer(
    const int* __restrict__ cnt,             // [2*HALF]
    const unsigned short* __restrict__ idx,  // [2*HALF][CAP]
    const float* __restrict__ tabA,          // [6144][64]
    const float* __restrict__ tabB,          // [6144][64]
    const float* __restrict__ Wa, const float* __restrict__ ba,
    float* __restrict__ outA,
    const float* __restrict__ Wb, const float* __restrict__ bb,
    float* __restrict__ outB,
    int do_relu) {
  __shared__ float4 lds_agg[NC][16][16];     // 20 KB
  const int side = blockIdx.x >= 384;
  const int r0   = (blockIdx.x - side * 384) * 16;
  const float4* tab = (const float4*)(side ? tabB : tabA);
  const float* W    = side ? Wb : Wa;
  const float* bias = side ? bb : ba;
  float* out        = side ? outB : outA;
  const int wave = threadIdx.x >> 6;
  const int lane = threadIdx.x & 63;
  const int g    = lane >> 4;
  const int e16  = lane & 15;

  // ---- gather phase: 20 (c,row) tasks for this wave ----
  for (int rr = wave * 4; rr < wave * 4 + 4; ++rr) {
    for (int c = 0; c < NC; ++c) {
      const int R = side * HALF + c * 6144 + r0 + rr;
      int n = cnt[R];
      n = n > CAP ? CAP : n;
      const unsigned short* l = idx + (size_t)R * CAP;
      float4 a0 = make_float4(0.f,0.f,0.f,0.f), a1 = a0, a2 = a0, a3 = a0;
      int i = 0;
      for (; i + 16 <= n; i += 16) {
        const int j0 = l[i + g], j1 = l[i + 4 + g];
        const int j2 = l[i + 8 + g], j3 = l[i + 12 + g];
        const float4 x0 = tab[j0 * 16 + e16];
        const float4 x1 = tab[j1 * 16 + e16];
        const float4 x2 = tab[j2 * 16 + e16];
        const float4 x3 = tab[j3 * 16 + e16];
        a0.x += x0.x; a0.y += x0.y; a0.z += x0.z; a0.w += x0.w;
        a1.x += x1.x; a1.y += x1.y; a1.z += x1.z; a1.w += x1.w;
        a2.x += x2.x; a2.y += x2.y; a2.z += x2.z; a2.w += x2.w;
        a3.x += x3.x; a3.y += x3.y; a3.z += x3.z; a3.w += x3.w;
      }
      for (; i + 4 <= n; i += 4) {
        const float4 x = tab[(int)l[i + g] * 16 + e16];
        a0.x += x.x; a0.y += x.y; a0.z += x.z; a0.w += x.w;
      }
      if (i + g < n) {
        const float4 x = tab[(int)l[i + g] * 16 + e16];
        a1.x += x.x; a1.y += x.y; a1.z += x.z; a1.w += x.w;
      }
      a0.x += a1.x + a2.x + a3.x;
      a0.y += a1.y + a2.y + a3.y;
      a0.z += a1.z + a2.z + a3.z;
      a0.w += a1.w + a2.w + a3.w;
      #pragma unroll
      for (int off = 16; off < 64; off <<= 1) {
        a0.x += __shfl_xor(a0.x, off, 64);
        a0.y += __shfl_xor(a0.y, off, 64);
        a0.z += __shfl_xor(a0.z, off, 64);
        a0.w += __shfl_xor(a0.w, off, 64);
      }
      if (g == 0) lds_agg[c][rr][e16] = a0;
    }
  }
  __syncthreads();

  // ---- GEMM phase: wave computes rows r0+wave*4 .. +3 ----
  float bs = 0.0f;
  #pragma unroll
  for (int c = 0; c < NC; ++c) bs += bias[c * 64 + lane];
  float acc[4] = {bs, bs, bs, bs};
  for (int c = 0; c < NC; ++c) {
    float w[64];
    #pragma unroll
    for (int d = 0; d < 64; ++d) w[d] = W[c * 4096 + d * 64 + lane];
    #pragma unroll
    for (int r = 0; r < 4; ++r) {
      #pragma unroll
      for (int d4 = 0; d4 < 16; ++d4) {
        const float4 a = lds_agg[c][wave * 4 + r][d4];   // LDS broadcast
        acc[r] = fmaf(a.x, w[d4 * 4 + 0], acc[r]);
        acc[r] = fmaf(a.y, w[d4 * 4 + 1], acc[r]);
        acc[r] = fmaf(a.z, w[d4 * 4 + 2], acc[r]);
        acc[r] = fmaf(a.w, w[d4 * 4 + 3], acc[r]);
      }
    }
  }
  #pragma unroll
  for (int r = 0; r < 4; ++r) {
    const float v = do_relu ? fmaxf(acc[r], 0.0f) : acc[r];
    out[(size_t)(r0 + wave * 4 + r) * 64 + lane] = v;
  }
}

// ---------------------------------------------------------------------------
// Decoder: logits[b,c] = sum_{d,e} z_u[u[b],d] * Q[c,d,e] * z_v[v[b],e]
// ---------------------------------------------------------------------------
__global__ __launch_bounds__(256) void k_decoder(
    const int* __restrict__ uu, const int* __restrict__ vv,
    const float* __restrict__ z_u, const float* __restrict__ z_v,
    const float* __restrict__ Q,   // C x 64 x 64
    float* __restrict__ out) {     // B x C
  const int lane = threadIdx.x & 63;
  const int wave = threadIdx.x >> 6;
  const int b = blockIdx.x * 4 + wave;
  const int ub = uu[b];
  const int vb = vv[b];
  const float zve = z_v[(size_t)vb * 64 + lane];
  const float* zu = z_u + (size_t)ub * 64;            // wave-uniform reads
  #pragma unroll
  for (int c = 0; c < NC; ++c) {
    const float* Qc = Q + c * 64 * 64;
    float t = 0.0f;
    #pragma unroll
    for (int d = 0; d < 64; ++d) t = fmaf(zu[d], Qc[d * 64 + lane], t);
    float p = t * zve;
    #pragma unroll
    for (int off = 32; off > 0; off >>= 1) p += __shfl_xor(p, off, 64);
    if (lane == 0) out[(size_t)b * NC + c] = p;
  }
}

extern "C" void kernel_launch(void* const* d_in, const int* in_sizes, int n_in,
                              void* d_out, int out_size, void* d_ws, size_t ws_size,
                              hipStream_t stream) {
  const int*   u     = (const int*)d_in[0];
  const int*   v     = (const int*)d_in[1];
  const float* u_emb = (const float*)d_in[2];
  const float* v_emb = (const float*)d_in[3];
  const float* W1u   = (const float*)d_in[4];
  const float* b1u   = (const float*)d_in[5];
  const float* W1v   = (const float*)d_in[6];
  const float* b1v   = (const float*)d_in[7];
  const float* W2u   = (const float*)d_in[8];
  const float* b2u   = (const float*)d_in[9];
  const float* W2v   = (const float*)d_in[10];
  const float* b2v   = (const float*)d_in[11];
  const float* Q     = (const float*)d_in[12];
  const float* adj   = (const float*)d_in[13];
  float* out = (float*)d_out;

  // ---- workspace carve-up (~22 MB) ----
  char* ws = (char*)d_ws;
  int* cnt = (int*)ws;                                       //   245,760 B
  unsigned short* idxL = (unsigned short*)(ws + 245760);     // 15,728,640 B
  char* fbase = ws + 245760 + 15728640;
  float* h_u = (float*)fbase;
  float* h_v = (float*)(fbase + 1572864);
  float* z_u = (float*)(fbase + 3145728);
  float* z_v = (float*)(fbase + 4718592);                    // ends ~22 MB

  // zero the counters (ws is poisoned 0xAA each call)
  hipMemsetAsync(cnt, 0, 2 * NC * 6144 * sizeof(int), stream);

  // One pass over adj -> CSR + CSC index lists (XCD-swizzled tiles)
  k_adj2idx<<<NC * 96 * 24, 256, 0, stream>>>(adj, cnt, idxL);

  // layer 1: fused gather+GEMM (both sides in one launch)
  k_layer<<<768, 256, 0, stream>>>(cnt, idxL, v_emb, u_emb,
                                   W1v, b1v, h_u, W1u, b1u, h_v, 1);
  // layer 2
  k_layer<<<768, 256, 0, stream>>>(cnt, idxL, h_v, h_u,
                                   W2u, b2u, z_u, W2v, b2v, z_v, 0);
  // bilinear decoder
  k_decoder<<<NB / 4, 256, 0, stream>>>(u, v, z_u, z_v, Q, out);
}